// Round 18
// baseline (198.129 us; speedup 1.0000x reference)
//
#include <hip/hip_runtime.h>
#include <hip/hip_bf16.h>
#include <math.h>

typedef __bf16 bf16;
typedef __bf16 bf16x8 __attribute__((ext_vector_type(8)));
typedef __bf16 bf16x4 __attribute__((ext_vector_type(4)));
typedef float f32x4 __attribute__((ext_vector_type(4)));
typedef float f32x16 __attribute__((ext_vector_type(16)));

#define MFMA16(a, b, c) __builtin_amdgcn_mfma_f32_16x16x32_bf16((a), (b), (c), 0, 0, 0)
#define MFMA32(a, b, c) __builtin_amdgcn_mfma_f32_32x32x16_bf16((a), (b), (c), 0, 0, 0)

__device__ __forceinline__ void gload_lds16(const void* g, void* l) {
  __builtin_amdgcn_global_load_lds((__attribute__((address_space(1))) void*)(g),
                                   (__attribute__((address_space(3))) void*)(l),
                                   16, 0, 0);
}

// ---------------- qkv_w fp32 -> Bflat bf16 repack ----------------
// Bflat bijection: n = {nb[>=7], wc[6], fc[5:4], r16[3:0]}, k = {s[9:5], hi[4:3], e[2:0]}
//   flat = nb*131072 + s*4096 + wc*2048 + fc*512 + hi*128 + r16*8 + e
// Consumer reads Bflat[nb*131072 + s*4096 + wc*2048 + fc*512 + lane*8 + e], lane = hi*16+r16
// = B[n = nb*128 + wc*64 + fc*16 + r16][k = s*32 + hi*8 + e]  (verified both directions).
// BUGFIX vs rounds 16/17: grid must cover ALL 3072 rows -> 3072 blocks (was 768: 3/4 of
// Bflat stayed poison; identical absmax across both rounds was the tell).
__global__ __launch_bounds__(256) void qkvrepack_kernel(const float* __restrict__ in,
                                                        bf16* __restrict__ outf) {
  int i = blockIdx.x * 256 + threadIdx.x;  // 786432 threads, 4 elems each (3072x1024)
  int n = i >> 8, k = (i & 255) * 4;
  float4 v = *(const float4*)&in[(size_t)n * 1024 + k];
  bf16x4 o;
  o[0] = (bf16)v.x; o[1] = (bf16)v.y; o[2] = (bf16)v.z; o[3] = (bf16)v.w;
  size_t flat = (size_t)((n >> 7) * 32 + (k >> 5)) * 4096 + ((n >> 6) & 1) * 2048 +
                ((n >> 4) & 3) * 512 + ((k >> 3) & 3) * 128 + (n & 15) * 8 + (k & 7);
  *(bf16x4*)&outf[flat] = o;
}

// ---------------- fp32 -> bf16 conversion (out_w) ----------------
__global__ __launch_bounds__(256) void f2bf_kernel(const float* __restrict__ in,
                                                   bf16* __restrict__ out) {
  int i = blockIdx.x * 256 + threadIdx.x;
  float4 v = ((const float4*)in)[i];
  bf16x4 o;
  o[0] = (bf16)v.x; o[1] = (bf16)v.y; o[2] = (bf16)v.z; o[3] = (bf16)v.w;
  *(bf16x4*)(out + (size_t)i * 4) = o;
}

// ---------------- ns = cond @ norm_w.T + 1 ----------------
__global__ __launch_bounds__(256) void ns_kernel(const float* __restrict__ cond,
                                                 const float* __restrict__ norm_w,
                                                 float* __restrict__ nsp1) {
  int tid = blockIdx.x * 256 + threadIdx.x;  // 8192 = 8 * 1024
  int b = tid >> 10, c = tid & 1023;
  const float4* wv = (const float4*)(norm_w + (size_t)c * 768);
  const float4* cv = (const float4*)(cond + (size_t)b * 768);
  float acc = 0.f;
#pragma unroll 8
  for (int i = 0; i < 192; ++i) {
    float4 w4 = wv[i], c4 = cv[i];
    acc += w4.x * c4.x + w4.y * c4.y + w4.z * c4.z + w4.w * c4.w;
  }
  nsp1[tid] = acc + 1.0f;
}

// ---------------- RMSNorm * (ns+1) -> bf16 ----------------
__global__ __launch_bounds__(256) void rmsnorm_kernel(const float* __restrict__ x,
                                                      const float* __restrict__ nsp1,
                                                      bf16* __restrict__ xn) {
  int lane = threadIdx.x & 63, w = threadIdx.x >> 6;
  int m = blockIdx.x * 4 + w;  // token id, 8192 total
  int b = m >> 10;
  const float* xp = x + (size_t)m * 1024 + lane * 16;
  float v[16];
  float ss = 0.f;
#pragma unroll
  for (int i = 0; i < 4; ++i) {
    float4 t4 = ((const float4*)xp)[i];
    v[4 * i + 0] = t4.x; v[4 * i + 1] = t4.y; v[4 * i + 2] = t4.z; v[4 * i + 3] = t4.w;
    ss += t4.x * t4.x + t4.y * t4.y + t4.z * t4.z + t4.w * t4.w;
  }
#pragma unroll
  for (int off = 32; off >= 1; off >>= 1) ss += __shfl_xor(ss, off);
  float r = rsqrtf(ss * (1.0f / 1024.0f) + 1e-6f);
  const float* np = nsp1 + (size_t)b * 1024 + lane * 16;
  bf16x8 o0, o1;
#pragma unroll
  for (int j = 0; j < 8; ++j) o0[j] = (bf16)(v[j] * np[j] * r);
#pragma unroll
  for (int j = 0; j < 8; ++j) o1[j] = (bf16)(v[8 + j] * np[8 + j] * r);
  bf16* op = xn + (size_t)m * 1024 + lane * 16;
  *(bf16x8*)op = o0;
  *(bf16x8*)(op + 8) = o1;
}

// ======== flat-B GEMM for qkv: 256x128 tile, A in LDS (ring-3), B direct from L2 ========
__global__ __launch_bounds__(512, 4) void gemmflat(const bf16* __restrict__ A,
                                                   const bf16* __restrict__ Bflat, int nbn,
                                                   bf16* __restrict__ qout, bf16* __restrict__ kout,
                                                   bf16* __restrict__ vtout,
                                                   const float* __restrict__ pos,
                                                   const float* __restrict__ scale) {
  constexpr int K = 1024;
  __shared__ __align__(16) bf16 sm[24576];  // 3 A-slots x 8192 elems = 48 KB
  const int t = threadIdx.x;
  const int cpx = gridDim.x >> 3;  // grid % 8 == 0
  const int bid = blockIdx.x;
  const int virt = (bid & 7) * cpx + (bid >> 3);
  const int nb = virt % nbn, bm = virt / nbn;
  const int m0 = bm * 256, n0 = nb * 128;
  const int lane = t & 63, wid = t >> 6;
  const int wr = wid >> 1, wc = wid & 1;  // 4x2 wave grid, wave tile 64x64
  const int r16 = lane & 15, hi = lane >> 4;

  // A staging (proven gemm256b scheme: inverse-swizzled source, linear LDS dest)
  const int tq = t >> 3, c8 = t & 7, cp = c8 ^ (tq & 7);
  const size_t gA = (size_t)(m0 + tq * 2 + (cp >> 2)) * K + (cp & 3) * 8;
  const size_t gj = (size_t)128 * K;
  const int ldst = t * 8;

  // A fragment read offsets (2 k32-rows packed per 128B LDS row, XOR-swizzled chunks)
  const int chunk = ((r16 & 1) * 4 + hi) ^ (r16 >> 1);
  int aoff[4];
#pragma unroll
  for (int fr = 0; fr < 4; ++fr) aoff[fr] = (wr * 32 + fr * 8 + (r16 >> 1)) * 64 + chunk * 8;

  // B direct-load base: per-lane coalesced 16B within the wave's (wc, fc, s) 1KB chunk
  const bf16* bfp = Bflat + (size_t)nb * 131072 + wc * 2048 + lane * 8;

  f32x4 acc[4][4] = {};
  bf16x8 bbuf[2][4];

#define STGA(tile_, slot_)                                             \
  {                                                                    \
    const bf16* as_ = A + gA + (size_t)(tile_) * 32;                   \
    gload_lds16(as_, &sm[(slot_) * 8192 + ldst]);                      \
    gload_lds16(as_ + gj, &sm[(slot_) * 8192 + 4096 + ldst]);          \
  }

  // prologue: A(0); B(0) -> bbuf[0]; A(1)   (issue order matters for vmcnt counting)
  STGA(0, 0);
#pragma unroll
  for (int fc = 0; fc < 4; ++fc) bbuf[0][fc] = *(const bf16x8*)(bfp + fc * 512);
  STGA(1, 1);

#pragma unroll
  for (int s = 0; s < 32; ++s) {
    if (s < 31) {
      asm volatile("s_waitcnt vmcnt(2)" ::: "memory");  // A(s)+B(s) landed; A(s+1) flying
    } else {
      asm volatile("s_waitcnt vmcnt(0)" ::: "memory");
    }
    __builtin_amdgcn_s_barrier();
    __builtin_amdgcn_sched_barrier(0);
    // issue next-step B into the other reg buffer; stage A(s+2) into ring slot
    if (s + 1 < 32) {
#pragma unroll
      for (int fc = 0; fc < 4; ++fc)
        bbuf[(s + 1) & 1][fc] = *(const bf16x8*)(bfp + (s + 1) * 4096 + fc * 512);
    }
    if (s + 2 < 32) STGA(s + 2, (s + 2) % 3);
    __builtin_amdgcn_sched_barrier(0);
    // A fragments from LDS slot s%3 (compiler inserts counted lgkmcnt before MFMA use)
    bf16x8 af[4];
    const bf16* base = &sm[(s % 3) * 8192];
#pragma unroll
    for (int fr = 0; fr < 4; ++fr) af[fr] = *(const bf16x8*)&base[aoff[fr]];
    __builtin_amdgcn_s_setprio(1);
#pragma unroll
    for (int fc = 0; fc < 4; ++fc)
#pragma unroll
      for (int fr = 0; fr < 4; ++fr) acc[fr][fc] = MFMA16(af[fr], bbuf[s & 1][fc], acc[fr][fc]);
    __builtin_amdgcn_s_setprio(0);
    __builtin_amdgcn_sched_barrier(0);
  }
#undef STGA

  // ---- fused epilogue (identical to previous rounds) ----
  const int p = n0 >> 10;  // uniform per block: 0=q, 1=k, 2=v
  if (p == 2) {
    const int hiq = ((hi & 1) << 1) | (hi >> 1);  // pi quad-swap for attn's b128 V reads
#pragma unroll
    for (int fr = 0; fr < 4; ++fr) {
      int mrow = m0 + wr * 64 + fr * 16 + hiq * 4;
      int b = mrow >> 10, s0 = mrow & 1023;
#pragma unroll
      for (int fc = 0; fc < 4; ++fc) {
        int n = n0 + wc * 64 + fc * 16 + r16;
        int d = n & 63, hh = (n >> 6) & 15;
        bf16x4 pk;
        pk[0] = (bf16)acc[fr][fc][0]; pk[1] = (bf16)acc[fr][fc][1];
        pk[2] = (bf16)acc[fr][fc][2]; pk[3] = (bf16)acc[fr][fc][3];
        *(bf16x4*)&vtout[(((size_t)(b * 16 + hh) * 64 + d) << 10) + s0] = pk;
      }
    }
  } else {
    const int hh = ((n0 + wc * 64) >> 6) & 15;
    const float LOG2E = 1.4426950408889634f;
    const float sqv = sqrtf(scale[hh]) * (p == 0 ? LOG2E : 1.0f);
    const float f = __expf(1.14472988584940017f +
                           0.0179897502011134460f * (float)((r16 & 7) * 16 + hh));
    const bool is_h = (r16 < 8);
    bf16* dst = (p == 0) ? qout : kout;
#pragma unroll
    for (int fr = 0; fr < 4; ++fr) {
      int mrow = m0 + wr * 64 + fr * 16 + hi * 4;
      int b = mrow >> 10, s0 = mrow & 1023;
      float rr[4];
#pragma unroll
      for (int r = 0; r < 4; ++r) {
        float ss = acc[fr][0][r] * acc[fr][0][r] + acc[fr][1][r] * acc[fr][1][r] +
                   acc[fr][2][r] * acc[fr][2][r] + acc[fr][3][r] * acc[fr][3][r];
        ss += __shfl_xor(ss, 1);
        ss += __shfl_xor(ss, 2);
        ss += __shfl_xor(ss, 4);
        ss += __shfl_xor(ss, 8);
        rr[r] = sqv * rsqrtf(ss + 1e-6f);
      }
#pragma unroll
      for (int r = 0; r < 4; ++r) {
        float2 pp = *(const float2*)&pos[(((size_t)b << 10) + s0 + r) * 2];
        float th = (is_h ? pp.x : pp.y) * f;
        float sv, cv;
        __sincosf(th, &sv, &cv);
        float x1 = acc[fr][0][r] * rr[r];
        float x2 = acc[fr][1][r] * rr[r];
        size_t rowb = (((size_t)(b * 16 + hh) << 10) + s0 + r) * 64;
        dst[rowb + r16]      = (bf16)(x1 * cv - x2 * sv);
        dst[rowb + 16 + r16] = (bf16)(x2 * cv + x1 * sv);
        dst[rowb + 32 + r16] = (bf16)(acc[fr][2][r] * rr[r]);
        dst[rowb + 48 + r16] = (bf16)(acc[fr][3][r] * rr[r]);
      }
    }
  }
}

// ---------------- 256x128-tile GEMM, ring-3 BK=32 — out-proj only (unchanged) ----------------
__global__ __launch_bounds__(512, 2) void gemm256b(const bf16* __restrict__ A,
                                                   const bf16* __restrict__ B, int nbn,
                                                   float* __restrict__ fout,
                                                   const float* __restrict__ skip) {
  constexpr int K = 1024;
  __shared__ __align__(16) bf16 sm[36864];  // 3 slots x (A 8192 + B 4096) = 72 KB
  const int t = threadIdx.x;
  const int cpx = gridDim.x >> 3;
  const int bid = blockIdx.x;
  const int virt = (bid & 7) * cpx + (bid >> 3);
  const int bn = virt % nbn, bm = virt / nbn;
  const int m0 = bm * 256, n0 = bn * 128;
  const int lane = t & 63, wid = t >> 6;
  const int wr = wid >> 1, wc = wid & 1;
  const int r16 = lane & 15, hi = lane >> 4;

  const int tq = t >> 3, c8 = t & 7, cp = c8 ^ (tq & 7);
  const size_t gA = (size_t)(m0 + tq * 2 + (cp >> 2)) * K + (cp & 3) * 8;
  const size_t gB = (size_t)(n0 + tq * 2 + (cp >> 2)) * K + (cp & 3) * 8;
  const size_t gj = (size_t)128 * K;
  const int ldst = t * 8;

  const int chunk = ((r16 & 1) * 4 + hi) ^ (r16 >> 1);
  int aoff[4], boff[4];
#pragma unroll
  for (int fr = 0; fr < 4; ++fr) aoff[fr] = (wr * 32 + fr * 8 + (r16 >> 1)) * 64 + chunk * 8;
#pragma unroll
  for (int fc = 0; fc < 4; ++fc)
    boff[fc] = (wc * 32 + fc * 8 + (r16 >> 1)) * 64 + chunk * 8 + 8192;

  f32x4 acc[4][4] = {};
  constexpr int NS = K >> 5;  // 32

#define STG(tile, slot)                                              \
  {                                                                  \
    const bf16* as_ = A + gA + (size_t)(tile) * 32;                  \
    const bf16* bs_ = B + gB + (size_t)(tile) * 32;                  \
    gload_lds16(as_, &sm[(slot) * 12288 + ldst]);                    \
    gload_lds16(as_ + gj, &sm[(slot) * 12288 + 4096 + ldst]);        \
    gload_lds16(bs_, &sm[(slot) * 12288 + 8192 + ldst]);             \
  }

  STG(0, 0);
  STG(1, 1);

  int sl = 0, sl2 = 2;
  for (int s = 0; s < NS; ++s) {
    if (s < NS - 1) {
      asm volatile("s_waitcnt vmcnt(3)" ::: "memory");
    } else {
      asm volatile("s_waitcnt vmcnt(0)" ::: "memory");
    }
    __builtin_amdgcn_s_barrier();
    __builtin_amdgcn_sched_barrier(0);
    if (s + 2 < NS) STG(s + 2, sl2);
    bf16x8 af[4], bfr[4];
    const bf16* base = &sm[sl * 12288];
#pragma unroll
    for (int fr = 0; fr < 4; ++fr) af[fr] = *(const bf16x8*)&base[aoff[fr]];
#pragma unroll
    for (int fc = 0; fc < 4; ++fc) bfr[fc] = *(const bf16x8*)&base[boff[fc]];
    __builtin_amdgcn_s_setprio(1);
#pragma unroll
    for (int fc = 0; fc < 4; ++fc)
#pragma unroll
      for (int fr = 0; fr < 4; ++fr) acc[fr][fc] = MFMA16(af[fr], bfr[fc], acc[fr][fc]);
    __builtin_amdgcn_s_setprio(0);
    sl = (sl == 2) ? 0 : sl + 1;
    sl2 = (sl2 == 2) ? 0 : sl2 + 1;
  }
#undef STG

#pragma unroll
  for (int fr = 0; fr < 4; ++fr) {
    int mrow = m0 + wr * 64 + fr * 16 + hi * 4;
#pragma unroll
    for (int fc = 0; fc < 4; ++fc) {
      int n = n0 + wc * 64 + fc * 16 + r16;
#pragma unroll
      for (int r = 0; r < 4; ++r) {
        size_t off = (size_t)(mrow + r) * 1024 + n;
        fout[off] = acc[fr][fc][r] + skip[off];
      }
    }
  }
}

// ---------------- flash attention v8b: 32x32 MFMA, depth-2 pipeline (unchanged) ----------------
__global__ __launch_bounds__(256, 4) void attn_kernel(const bf16* __restrict__ q,
                                                      const bf16* __restrict__ k,
                                                      const bf16* __restrict__ vt,
                                                      bf16* __restrict__ o) {
  int bid = blockIdx.x;  // 1024 blocks
  int virt = (bid & 7) * 128 + (bid >> 3);
  const int bh = virt >> 3;     // (b*16+h)
  const int qt = virt & 7;      // q-tile of 128
  const int b = bh >> 4, h = bh & 15;
  const int t = threadIdx.x, lane = t & 63, w = t >> 6;  // 4 waves
  const int l31 = lane & 31, h2 = lane >> 5;

  __shared__ bf16 lK[2][4096];
  __shared__ bf16 lV[2][4096];

  const bf16* kp = k + (size_t)bh * 65536;
  const bf16* vp = vt + (size_t)bh * 65536;  // (d, s-pi) layout

  const bf16* qp = q + ((size_t)bh * 1024 + qt * 128 + w * 32) * 64;
  bf16x8 qf[4];
#pragma unroll
  for (int df = 0; df < 4; ++df)
    qf[df] = *(const bf16x8*)&qp[l31 * 64 + df * 16 + h2 * 8];

  bf16x8 ones;
#pragma unroll
  for (int i = 0; i < 8; ++i) ones[i] = (bf16)1.0f;

  const int srow0 = t >> 3, sc0 = t & 7;

  f32x16 oacc0 = {}, oacc1 = {}, lacc = {};

#define STGA(kt_, buf_)                                                            \
  {                                                                                \
    const bf16* kb_ = kp + (kt_) * 4096;                                           \
    const bf16* vb_ = vp + (kt_) * 64;                                             \
    _Pragma("unroll") for (int j = 0; j < 2; ++j) {                                \
      int row = srow0 + j * 32;                                                    \
      int se = ((sc0 ^ (row & 7)) << 3);                                           \
      gload_lds16(kb_ + (size_t)row * 64 + se, &lK[buf_][t * 8 + j * 2048]);       \
      gload_lds16(vb_ + (size_t)row * 1024 + se, &lV[buf_][t * 8 + j * 2048]);     \
    }                                                                              \
  }

  STGA(0, 0);
  STGA(1, 1);

  for (int kt = 0; kt < 16; ++kt) {
    const int cur = kt & 1;
    if (kt < 15) {
      asm volatile("s_waitcnt vmcnt(4)" ::: "memory");
    } else {
      asm volatile("s_waitcnt vmcnt(0)" ::: "memory");
    }
    __builtin_amdgcn_s_barrier();
    __builtin_amdgcn_sched_barrier(0);
    f32x16 sa0 = {}, sa1 = {};
    __builtin_amdgcn_s_setprio(1);
#pragma unroll
    for (int df = 0; df < 4; ++df) {
      int sw = l31 & 7;
      int ce = (((2 * df + h2) ^ sw) << 3);
      bf16x8 kf0 = *(const bf16x8*)&lK[cur][l31 * 64 + ce];
      bf16x8 kf1 = *(const bf16x8*)&lK[cur][(32 + l31) * 64 + ce];
      sa0 = MFMA32(kf0, qf[df], sa0);
      sa1 = MFMA32(kf1, qf[df], sa1);
    }
    __builtin_amdgcn_s_setprio(0);
    bf16x8 pa[4];
#pragma unroll
    for (int e = 0; e < 8; ++e) {
      pa[0][e] = (bf16)exp2f(sa0[e]);
      pa[1][e] = (bf16)exp2f(sa0[e + 8]);
      pa[2][e] = (bf16)exp2f(sa1[e]);
      pa[3][e] = (bf16)exp2f(sa1[e + 8]);
    }
    __builtin_amdgcn_s_setprio(1);
#pragma unroll
    for (int pk = 0; pk < 4; ++pk) {
      lacc = MFMA32(pa[pk], ones, lacc);
#pragma unroll
      for (int db = 0; db < 2; ++db) {
        int row = db * 32 + l31, sw = row & 7;
        bf16x8 vf = *(const bf16x8*)&lV[cur][row * 64 + (((2 * pk + h2) ^ sw) << 3)];
        if (db == 0) oacc0 = MFMA32(pa[pk], vf, oacc0);
        else         oacc1 = MFMA32(pa[pk], vf, oacc1);
      }
    }
    __builtin_amdgcn_s_setprio(0);
    __builtin_amdgcn_sched_barrier(0);
    __builtin_amdgcn_s_barrier();
    __builtin_amdgcn_sched_barrier(0);
    if (kt < 14) STGA(kt + 2, cur);
  }
#undef STGA

  f32x16 inv;
#pragma unroll
  for (int r = 0; r < 16; ++r) inv[r] = 1.f / lacc[r];
#pragma unroll
  for (int r = 0; r < 16; ++r) {
    int qrow = qt * 128 + w * 32 + (r & 3) + 8 * (r >> 2) + 4 * h2;
    size_t rowb = ((size_t)b * 1024 + qrow) * 1024 + h * 64;
    o[rowb + l31]      = (bf16)(oacc0[r] * inv[r]);
    o[rowb + 32 + l31] = (bf16)(oacc1[r] * inv[r]);
  }
}

extern "C" void kernel_launch(void* const* d_in, const int* in_sizes, int n_in,
                              void* d_out, int out_size, void* d_ws, size_t ws_size,
                              hipStream_t stream) {
  const float* x      = (const float*)d_in[0];  // (8,32,32,1024)
  const float* pos    = (const float*)d_in[1];  // (8,32,32,2)
  const float* cond   = (const float*)d_in[2];  // (8,768)
  const float* norm_w = (const float*)d_in[3];  // (1024,768)
  const float* qkv_w  = (const float*)d_in[4];  // (3072,1024)
  const float* out_w  = (const float*)d_in[5];  // (1024,1024)
  const float* scale  = (const float*)d_in[6];  // (16,)
  float* out = (float*)d_out;

  char* ws = (char*)d_ws;
  bf16* xn        = (bf16*)(ws + 0);           // 16.8 MB (reused as o_attn)
  bf16* Bflat     = (bf16*)(ws + 16777216);    // 6.3 MB (repacked qkv_w)
  bf16* out_w_bf  = (bf16*)(ws + 23068672);    // 2.1 MB
  float* nsp1     = (float*)(ws + 25165824);   // 32 KB
  bf16* qraw      = (bf16*)(ws + 25198592);    // 16.8 MB
  bf16* kraw      = (bf16*)(ws + 41975808);    // 16.8 MB
  bf16* vt        = (bf16*)(ws + 58753024);    // 16.8 MB
  bf16* o_attn    = xn;

  qkvrepack_kernel<<<3072, 256, 0, stream>>>(qkv_w, Bflat);
  f2bf_kernel<<<1024, 256, 0, stream>>>(out_w, out_w_bf);
  ns_kernel<<<32, 256, 0, stream>>>(cond, norm_w, nsp1);
  rmsnorm_kernel<<<2048, 256, 0, stream>>>(x, nsp1, xn);
  gemmflat<<<768, 512, 0, stream>>>(xn, Bflat, 24, qraw, kraw, vt, pos, scale);
  attn_kernel<<<1024, 256, 0, stream>>>(qraw, kraw, vt, o_attn);
  gemm256b<<<256, 512, 0, stream>>>(o_attn, out_w_bf, 8, out, x);
}

// Round 19
// 185.885 us; speedup vs baseline: 1.0659x; 1.0659x over previous
//
#include <hip/hip_runtime.h>
#include <hip/hip_bf16.h>
#include <math.h>

typedef __bf16 bf16;
typedef __bf16 bf16x8 __attribute__((ext_vector_type(8)));
typedef __bf16 bf16x4 __attribute__((ext_vector_type(4)));
typedef float f32x4 __attribute__((ext_vector_type(4)));
typedef float f32x16 __attribute__((ext_vector_type(16)));

#define MFMA16(a, b, c) __builtin_amdgcn_mfma_f32_16x16x32_bf16((a), (b), (c), 0, 0, 0)
#define MFMA32(a, b, c) __builtin_amdgcn_mfma_f32_32x32x16_bf16((a), (b), (c), 0, 0, 0)

__device__ __forceinline__ void gload_lds16(const void* g, void* l) {
  __builtin_amdgcn_global_load_lds((__attribute__((address_space(1))) void*)(g),
                                   (__attribute__((address_space(3))) void*)(l),
                                   16, 0, 0);
}

// ---------------- fp32 -> bf16 conversion (qkv_w and out_w in one launch) ----------------
__global__ __launch_bounds__(256) void f2bf_kernel(const float* __restrict__ in0,
                                                   bf16* __restrict__ out0,
                                                   const float* __restrict__ in1,
                                                   bf16* __restrict__ out1, int n0) {
  int i = blockIdx.x * 256 + threadIdx.x;
  const float* in = (i < n0) ? in0 : in1;
  bf16* out = (i < n0) ? out0 : out1;
  int j = (i < n0) ? i : i - n0;
  float4 v = ((const float4*)in)[j];
  bf16x4 o;
  o[0] = (bf16)v.x; o[1] = (bf16)v.y; o[2] = (bf16)v.z; o[3] = (bf16)v.w;
  *(bf16x4*)(out + (size_t)j * 4) = o;
}

// ---------------- ns = cond @ norm_w.T + 1 ----------------
__global__ __launch_bounds__(256) void ns_kernel(const float* __restrict__ cond,
                                                 const float* __restrict__ norm_w,
                                                 float* __restrict__ nsp1) {
  int tid = blockIdx.x * 256 + threadIdx.x;  // 8192 = 8 * 1024
  int b = tid >> 10, c = tid & 1023;
  const float4* wv = (const float4*)(norm_w + (size_t)c * 768);
  const float4* cv = (const float4*)(cond + (size_t)b * 768);
  float acc = 0.f;
#pragma unroll 8
  for (int i = 0; i < 192; ++i) {
    float4 w4 = wv[i], c4 = cv[i];
    acc += w4.x * c4.x + w4.y * c4.y + w4.z * c4.z + w4.w * c4.w;
  }
  nsp1[tid] = acc + 1.0f;
}

// ---------------- RMSNorm * (ns+1) -> bf16 ----------------
__global__ __launch_bounds__(256) void rmsnorm_kernel(const float* __restrict__ x,
                                                      const float* __restrict__ nsp1,
                                                      bf16* __restrict__ xn) {
  int lane = threadIdx.x & 63, w = threadIdx.x >> 6;
  int m = blockIdx.x * 4 + w;  // token id, 8192 total
  int b = m >> 10;
  const float* xp = x + (size_t)m * 1024 + lane * 16;
  float v[16];
  float ss = 0.f;
#pragma unroll
  for (int i = 0; i < 4; ++i) {
    float4 t4 = ((const float4*)xp)[i];
    v[4 * i + 0] = t4.x; v[4 * i + 1] = t4.y; v[4 * i + 2] = t4.z; v[4 * i + 3] = t4.w;
    ss += t4.x * t4.x + t4.y * t4.y + t4.z * t4.z + t4.w * t4.w;
  }
#pragma unroll
  for (int off = 32; off >= 1; off >>= 1) ss += __shfl_xor(ss, off);
  float r = rsqrtf(ss * (1.0f / 1024.0f) + 1e-6f);
  const float* np = nsp1 + (size_t)b * 1024 + lane * 16;
  bf16x8 o0, o1;
#pragma unroll
  for (int j = 0; j < 8; ++j) o0[j] = (bf16)(v[j] * np[j] * r);
#pragma unroll
  for (int j = 0; j < 8; ++j) o1[j] = (bf16)(v[8 + j] * np[8 + j] * r);
  bf16* op = xn + (size_t)m * 1024 + lane * 16;
  *(bf16x8*)op = o0;
  *(bf16x8*)(op + 8) = o1;
}

// ======== GEMM for qkv: 256x128 tile, BK=64, ring-3, phase interleave (best: 76.3us) ========
__global__ __launch_bounds__(512, 2) void gemm8p(const bf16* __restrict__ A,
                                                 const bf16* __restrict__ B, int nbn,
                                                 bf16* __restrict__ qout, bf16* __restrict__ kout,
                                                 bf16* __restrict__ vtout,
                                                 const float* __restrict__ pos,
                                                 const float* __restrict__ scale) {
  constexpr int K = 1024;
  __shared__ __align__(16) bf16 sm[73728];  // 3 slots x (A 16384 + B 8192 elems) = 144 KB
  const int t = threadIdx.x;
  const int cpx = gridDim.x >> 3;  // grid % 8 == 0
  const int bid = blockIdx.x;
  const int virt = (bid & 7) * cpx + (bid >> 3);
  const int bn = virt % nbn, bm = virt / nbn;
  const int m0 = bm * 256, n0 = bn * 128;
  const int lane = t & 63, wid = t >> 6;
  const int wr = wid >> 1, wc = wid & 1;  // 4x2 wave grid, wave tile 64x64
  const int r16 = lane & 15, hi = lane >> 4;
  const int sw = r16 & 7;

  const int row0 = t >> 3;
  const int gc = (t & 7) ^ (row0 & 7);
  const bf16* gAb = A + (size_t)(m0 + row0) * K + gc * 8;
  const bf16* gBb = B + (size_t)(n0 + row0) * K + gc * 8;
  const size_t rstep = (size_t)64 * K;
  const int ldst = t * 8;

  int aoff2[4][2], boff2[4][2];
#pragma unroll
  for (int fr = 0; fr < 4; ++fr)
#pragma unroll
    for (int ks = 0; ks < 2; ++ks) {
      aoff2[fr][ks] = (wr * 64 + fr * 16 + r16) * 64 + (((ks * 4 + hi) ^ sw) << 3);
      boff2[fr][ks] = 16384 + (wc * 64 + fr * 16 + r16) * 64 + (((ks * 4 + hi) ^ sw) << 3);
    }

  f32x4 acc[4][4] = {};

#define STG2(tile_, slot_, pr_)                                                       \
  {                                                                                   \
    if ((pr_) < 2) {                                                                  \
      gload_lds16(gAb + rstep * (2 * (pr_)) + (size_t)(tile_) * 64,                   \
                  &sm[(slot_) * 24576 + (2 * (pr_)) * 4096 + ldst]);                  \
      gload_lds16(gAb + rstep * (2 * (pr_) + 1) + (size_t)(tile_) * 64,               \
                  &sm[(slot_) * 24576 + (2 * (pr_) + 1) * 4096 + ldst]);              \
    } else {                                                                          \
      gload_lds16(gBb + (size_t)(tile_) * 64, &sm[(slot_) * 24576 + 16384 + ldst]);   \
      gload_lds16(gBb + rstep + (size_t)(tile_) * 64,                                 \
                  &sm[(slot_) * 24576 + 20480 + ldst]);                               \
    }                                                                                 \
  }

  STG2(0, 0, 0); STG2(0, 0, 1); STG2(0, 0, 2);
  STG2(1, 1, 0); STG2(1, 1, 1); STG2(1, 1, 2);

  int sl = 0, sl2 = 2;
  for (int s = 0; s < 16; ++s) {
    if (s < 15) {
      asm volatile("s_waitcnt vmcnt(6)" ::: "memory");
    } else {
      asm volatile("s_waitcnt vmcnt(0)" ::: "memory");
    }
    __builtin_amdgcn_s_barrier();
    __builtin_amdgcn_sched_barrier(0);
    const bf16* base = &sm[sl * 24576];
    const bool st = (s + 2 < 16);
    bf16x8 ball[4][2], a2[2][2];
#pragma unroll
    for (int fc = 0; fc < 4; ++fc)
#pragma unroll
      for (int ks = 0; ks < 2; ++ks) ball[fc][ks] = *(const bf16x8*)&base[boff2[fc][ks]];
#pragma unroll
    for (int i = 0; i < 2; ++i)
#pragma unroll
      for (int ks = 0; ks < 2; ++ks) a2[i][ks] = *(const bf16x8*)&base[aoff2[i][ks]];
    if (st) { STG2(s + 2, sl2, 0); STG2(s + 2, sl2, 1); }
    asm volatile("s_waitcnt lgkmcnt(0)" ::: "memory");
    __builtin_amdgcn_sched_barrier(0);
    __builtin_amdgcn_s_setprio(1);
#pragma unroll
    for (int ks = 0; ks < 2; ++ks)
#pragma unroll
      for (int fc = 0; fc < 4; ++fc)
#pragma unroll
        for (int i = 0; i < 2; ++i)
          acc[i][fc] = MFMA16(a2[i][ks], ball[fc][ks], acc[i][fc]);
    __builtin_amdgcn_s_setprio(0);
    __builtin_amdgcn_sched_barrier(0);
    __builtin_amdgcn_s_barrier();
    bf16x8 a3[2][2];
#pragma unroll
    for (int i = 0; i < 2; ++i)
#pragma unroll
      for (int ks = 0; ks < 2; ++ks) a3[i][ks] = *(const bf16x8*)&base[aoff2[2 + i][ks]];
    if (st) STG2(s + 2, sl2, 2);
    asm volatile("s_waitcnt lgkmcnt(0)" ::: "memory");
    __builtin_amdgcn_sched_barrier(0);
    __builtin_amdgcn_s_setprio(1);
#pragma unroll
    for (int ks = 0; ks < 2; ++ks)
#pragma unroll
      for (int fc = 0; fc < 4; ++fc)
#pragma unroll
        for (int i = 0; i < 2; ++i)
          acc[2 + i][fc] = MFMA16(a3[i][ks], ball[fc][ks], acc[2 + i][fc]);
    __builtin_amdgcn_s_setprio(0);
    __builtin_amdgcn_sched_barrier(0);
    __builtin_amdgcn_s_barrier();
    sl = (sl == 2) ? 0 : sl + 1;
    sl2 = (sl2 == 2) ? 0 : sl2 + 1;
  }
#undef STG2

  const int p = n0 >> 10;  // uniform per block: 0=q, 1=k, 2=v
  if (p == 2) {
    const int hiq = ((hi & 1) << 1) | (hi >> 1);  // pi quad-swap for attn's b128 V reads
#pragma unroll
    for (int fr = 0; fr < 4; ++fr) {
      int mrow = m0 + wr * 64 + fr * 16 + hiq * 4;
      int b = mrow >> 10, s0 = mrow & 1023;
#pragma unroll
      for (int fc = 0; fc < 4; ++fc) {
        int n = n0 + wc * 64 + fc * 16 + r16;
        int d = n & 63, hh = (n >> 6) & 15;
        bf16x4 pk;
        pk[0] = (bf16)acc[fr][fc][0]; pk[1] = (bf16)acc[fr][fc][1];
        pk[2] = (bf16)acc[fr][fc][2]; pk[3] = (bf16)acc[fr][fc][3];
        *(bf16x4*)&vtout[(((size_t)(b * 16 + hh) * 64 + d) << 10) + s0] = pk;
      }
    }
  } else {
    const int hh = ((n0 + wc * 64) >> 6) & 15;
    const float LOG2E = 1.4426950408889634f;
    const float sqv = sqrtf(scale[hh]) * (p == 0 ? LOG2E : 1.0f);
    const float f = __expf(1.14472988584940017f +
                           0.0179897502011134460f * (float)((r16 & 7) * 16 + hh));
    const bool is_h = (r16 < 8);
    bf16* dst = (p == 0) ? qout : kout;
#pragma unroll
    for (int fr = 0; fr < 4; ++fr) {
      int mrow = m0 + wr * 64 + fr * 16 + hi * 4;
      int b = mrow >> 10, s0 = mrow & 1023;
      float rr[4];
#pragma unroll
      for (int r = 0; r < 4; ++r) {
        float ss = acc[fr][0][r] * acc[fr][0][r] + acc[fr][1][r] * acc[fr][1][r] +
                   acc[fr][2][r] * acc[fr][2][r] + acc[fr][3][r] * acc[fr][3][r];
        ss += __shfl_xor(ss, 1);
        ss += __shfl_xor(ss, 2);
        ss += __shfl_xor(ss, 4);
        ss += __shfl_xor(ss, 8);
        rr[r] = sqv * rsqrtf(ss + 1e-6f);
      }
#pragma unroll
      for (int r = 0; r < 4; ++r) {
        float2 pp = *(const float2*)&pos[(((size_t)b << 10) + s0 + r) * 2];
        float th = (is_h ? pp.x : pp.y) * f;
        float sv, cv;
        __sincosf(th, &sv, &cv);
        float x1 = acc[fr][0][r] * rr[r];
        float x2 = acc[fr][1][r] * rr[r];
        size_t rowb = (((size_t)(b * 16 + hh) << 10) + s0 + r) * 64;
        dst[rowb + r16]      = (bf16)(x1 * cv - x2 * sv);
        dst[rowb + 16 + r16] = (bf16)(x2 * cv + x1 * sv);
        dst[rowb + 32 + r16] = (bf16)(acc[fr][2][r] * rr[r]);
        dst[rowb + 48 + r16] = (bf16)(acc[fr][3][r] * rr[r]);
      }
    }
  }
}

// ---------------- 256x128-tile GEMM, ring-3 BK=32 — out-proj only ----------------
__global__ __launch_bounds__(512, 2) void gemm256b(const bf16* __restrict__ A,
                                                   const bf16* __restrict__ B, int nbn,
                                                   float* __restrict__ fout,
                                                   const float* __restrict__ skip) {
  constexpr int K = 1024;
  __shared__ __align__(16) bf16 sm[36864];  // 3 slots x (A 8192 + B 4096) = 72 KB
  const int t = threadIdx.x;
  const int cpx = gridDim.x >> 3;
  const int bid = blockIdx.x;
  const int virt = (bid & 7) * cpx + (bid >> 3);
  const int bn = virt % nbn, bm = virt / nbn;
  const int m0 = bm * 256, n0 = bn * 128;
  const int lane = t & 63, wid = t >> 6;
  const int wr = wid >> 1, wc = wid & 1;
  const int r16 = lane & 15, hi = lane >> 4;

  const int tq = t >> 3, c8 = t & 7, cp = c8 ^ (tq & 7);
  const size_t gA = (size_t)(m0 + tq * 2 + (cp >> 2)) * K + (cp & 3) * 8;
  const size_t gB = (size_t)(n0 + tq * 2 + (cp >> 2)) * K + (cp & 3) * 8;
  const size_t gj = (size_t)128 * K;
  const int ldst = t * 8;

  const int chunk = ((r16 & 1) * 4 + hi) ^ (r16 >> 1);
  int aoff[4], boff[4];
#pragma unroll
  for (int fr = 0; fr < 4; ++fr) aoff[fr] = (wr * 32 + fr * 8 + (r16 >> 1)) * 64 + chunk * 8;
#pragma unroll
  for (int fc = 0; fc < 4; ++fc)
    boff[fc] = (wc * 32 + fc * 8 + (r16 >> 1)) * 64 + chunk * 8 + 8192;

  f32x4 acc[4][4] = {};
  constexpr int NS = K >> 5;  // 32

#define STG(tile, slot)                                              \
  {                                                                  \
    const bf16* as_ = A + gA + (size_t)(tile) * 32;                  \
    const bf16* bs_ = B + gB + (size_t)(tile) * 32;                  \
    gload_lds16(as_, &sm[(slot) * 12288 + ldst]);                    \
    gload_lds16(as_ + gj, &sm[(slot) * 12288 + 4096 + ldst]);        \
    gload_lds16(bs_, &sm[(slot) * 12288 + 8192 + ldst]);             \
  }

  STG(0, 0);
  STG(1, 1);

  int sl = 0, sl2 = 2;
  for (int s = 0; s < NS; ++s) {
    if (s < NS - 1) {
      asm volatile("s_waitcnt vmcnt(3)" ::: "memory");
    } else {
      asm volatile("s_waitcnt vmcnt(0)" ::: "memory");
    }
    __builtin_amdgcn_s_barrier();
    __builtin_amdgcn_sched_barrier(0);
    if (s + 2 < NS) STG(s + 2, sl2);
    bf16x8 af[4], bfr[4];
    const bf16* base = &sm[sl * 12288];
#pragma unroll
    for (int fr = 0; fr < 4; ++fr) af[fr] = *(const bf16x8*)&base[aoff[fr]];
#pragma unroll
    for (int fc = 0; fc < 4; ++fc) bfr[fc] = *(const bf16x8*)&base[boff[fc]];
    __builtin_amdgcn_s_setprio(1);
#pragma unroll
    for (int fc = 0; fc < 4; ++fc)
#pragma unroll
      for (int fr = 0; fr < 4; ++fr) acc[fr][fc] = MFMA16(af[fr], bfr[fc], acc[fr][fc]);
    __builtin_amdgcn_s_setprio(0);
    sl = (sl == 2) ? 0 : sl + 1;
    sl2 = (sl2 == 2) ? 0 : sl2 + 1;
  }
#undef STG

#pragma unroll
  for (int fr = 0; fr < 4; ++fr) {
    int mrow = m0 + wr * 64 + fr * 16 + hi * 4;
#pragma unroll
    for (int fc = 0; fc < 4; ++fc) {
      int n = n0 + wc * 64 + fc * 16 + r16;
#pragma unroll
      for (int r = 0; r < 4; ++r) {
        size_t off = (size_t)(mrow + r) * 1024 + n;
        fout[off] = acc[fr][fc][r] + skip[off];
      }
    }
  }
}

// ---------------- flash attention v8b: 32x32 MFMA, depth-2 pipeline, bounds(256,4) ----------------
__global__ __launch_bounds__(256, 4) void attn_kernel(const bf16* __restrict__ q,
                                                      const bf16* __restrict__ k,
                                                      const bf16* __restrict__ vt,
                                                      bf16* __restrict__ o) {
  int bid = blockIdx.x;  // 1024 blocks
  int virt = (bid & 7) * 128 + (bid >> 3);
  const int bh = virt >> 3;     // (b*16+h)
  const int qt = virt & 7;      // q-tile of 128
  const int b = bh >> 4, h = bh & 15;
  const int t = threadIdx.x, lane = t & 63, w = t >> 6;  // 4 waves
  const int l31 = lane & 31, h2 = lane >> 5;

  __shared__ bf16 lK[2][4096];
  __shared__ bf16 lV[2][4096];

  const bf16* kp = k + (size_t)bh * 65536;
  const bf16* vp = vt + (size_t)bh * 65536;  // (d, s-pi) layout

  const bf16* qp = q + ((size_t)bh * 1024 + qt * 128 + w * 32) * 64;
  bf16x8 qf[4];
#pragma unroll
  for (int df = 0; df < 4; ++df)
    qf[df] = *(const bf16x8*)&qp[l31 * 64 + df * 16 + h2 * 8];

  bf16x8 ones;
#pragma unroll
  for (int i = 0; i < 8; ++i) ones[i] = (bf16)1.0f;

  const int srow0 = t >> 3, sc0 = t & 7;

  f32x16 oacc0 = {}, oacc1 = {}, lacc = {};

#define STGA(kt_, buf_)                                                            \
  {                                                                                \
    const bf16* kb_ = kp + (kt_) * 4096;                                           \
    const bf16* vb_ = vp + (kt_) * 64;                                             \
    _Pragma("unroll") for (int j = 0; j < 2; ++j) {                                \
      int row = srow0 + j * 32;                                                    \
      int se = ((sc0 ^ (row & 7)) << 3);                                           \
      gload_lds16(kb_ + (size_t)row * 64 + se, &lK[buf_][t * 8 + j * 2048]);       \
      gload_lds16(vb_ + (size_t)row * 1024 + se, &lV[buf_][t * 8 + j * 2048]);     \
    }                                                                              \
  }

  STGA(0, 0);
  STGA(1, 1);

  for (int kt = 0; kt < 16; ++kt) {
    const int cur = kt & 1;
    if (kt < 15) {
      asm volatile("s_waitcnt vmcnt(4)" ::: "memory");
    } else {
      asm volatile("s_waitcnt vmcnt(0)" ::: "memory");
    }
    __builtin_amdgcn_s_barrier();
    __builtin_amdgcn_sched_barrier(0);
    f32x16 sa0 = {}, sa1 = {};
    __builtin_amdgcn_s_setprio(1);
#pragma unroll
    for (int df = 0; df < 4; ++df) {
      int sw = l31 & 7;
      int ce = (((2 * df + h2) ^ sw) << 3);
      bf16x8 kf0 = *(const bf16x8*)&lK[cur][l31 * 64 + ce];
      bf16x8 kf1 = *(const bf16x8*)&lK[cur][(32 + l31) * 64 + ce];
      sa0 = MFMA32(kf0, qf[df], sa0);
      sa1 = MFMA32(kf1, qf[df], sa1);
    }
    __builtin_amdgcn_s_setprio(0);
    bf16x8 pa[4];
#pragma unroll
    for (int e = 0; e < 8; ++e) {
      pa[0][e] = (bf16)exp2f(sa0[e]);
      pa[1][e] = (bf16)exp2f(sa0[e + 8]);
      pa[2][e] = (bf16)exp2f(sa1[e]);
      pa[3][e] = (bf16)exp2f(sa1[e + 8]);
    }
    __builtin_amdgcn_s_setprio(1);
#pragma unroll
    for (int pk = 0; pk < 4; ++pk) {
      lacc = MFMA32(pa[pk], ones, lacc);
#pragma unroll
      for (int db = 0; db < 2; ++db) {
        int row = db * 32 + l31, sw = row & 7;
        bf16x8 vf = *(const bf16x8*)&lV[cur][row * 64 + (((2 * pk + h2) ^ sw) << 3)];
        if (db == 0) oacc0 = MFMA32(pa[pk], vf, oacc0);
        else         oacc1 = MFMA32(pa[pk], vf, oacc1);
      }
    }
    __builtin_amdgcn_s_setprio(0);
    __builtin_amdgcn_sched_barrier(0);
    __builtin_amdgcn_s_barrier();
    __builtin_amdgcn_sched_barrier(0);
    if (kt < 14) STGA(kt + 2, cur);
  }
#undef STGA

  f32x16 inv;
#pragma unroll
  for (int r = 0; r < 16; ++r) inv[r] = 1.f / lacc[r];
#pragma unroll
  for (int r = 0; r < 16; ++r) {
    int qrow = qt * 128 + w * 32 + (r & 3) + 8 * (r >> 2) + 4 * h2;
    size_t rowb = ((size_t)b * 1024 + qrow) * 1024 + h * 64;
    o[rowb + l31]      = (bf16)(oacc0[r] * inv[r]);
    o[rowb + 32 + l31] = (bf16)(oacc1[r] * inv[r]);
  }
}

extern "C" void kernel_launch(void* const* d_in, const int* in_sizes, int n_in,
                              void* d_out, int out_size, void* d_ws, size_t ws_size,
                              hipStream_t stream) {
  const float* x      = (const float*)d_in[0];  // (8,32,32,1024)
  const float* pos    = (const float*)d_in[1];  // (8,32,32,2)
  const float* cond   = (const float*)d_in[2];  // (8,768)
  const float* norm_w = (const float*)d_in[3];  // (1024,768)
  const float* qkv_w  = (const float*)d_in[4];  // (3072,1024)
  const float* out_w  = (const float*)d_in[5];  // (1024,1024)
  const float* scale  = (const float*)d_in[6];  // (16,)
  float* out = (float*)d_out;

  char* ws = (char*)d_ws;
  bf16* xn        = (bf16*)(ws + 0);           // 16.8 MB (reused as o_attn)
  bf16* qkv_w_bf  = (bf16*)(ws + 16777216);    // 6.3 MB
  bf16* out_w_bf  = (bf16*)(ws + 23068672);    // 2.1 MB
  float* nsp1     = (float*)(ws + 25165824);   // 32 KB
  bf16* qraw      = (bf16*)(ws + 25198592);    // 16.8 MB
  bf16* kraw      = (bf16*)(ws + 41975808);    // 16.8 MB
  bf16* vt        = (bf16*)(ws + 58753024);    // 16.8 MB
  bf16* o_attn    = xn;

  f2bf_kernel<<<4096, 256, 0, stream>>>(qkv_w, qkv_w_bf, out_w, out_w_bf, 786432);
  ns_kernel<<<32, 256, 0, stream>>>(cond, norm_w, nsp1);
  rmsnorm_kernel<<<2048, 256, 0, stream>>>(x, nsp1, xn);
  gemm8p<<<768, 512, 0, stream>>>(xn, qkv_w_bf, 24, qraw, kraw, vt, pos, scale);
  attn_kernel<<<1024, 256, 0, stream>>>(qraw, kraw, vt, o_attn);
  gemm256b<<<256, 512, 0, stream>>>(o_attn, out_w_bf, 8, out, x);
}

// Round 20
// 182.886 us; speedup vs baseline: 1.0833x; 1.0164x over previous
//
#include <hip/hip_runtime.h>
#include <hip/hip_bf16.h>
#include <math.h>

typedef __bf16 bf16;
typedef __bf16 bf16x8 __attribute__((ext_vector_type(8)));
typedef __bf16 bf16x4 __attribute__((ext_vector_type(4)));
typedef float f32x4 __attribute__((ext_vector_type(4)));
typedef float f32x16 __attribute__((ext_vector_type(16)));

#define MFMA16(a, b, c) __builtin_amdgcn_mfma_f32_16x16x32_bf16((a), (b), (c), 0, 0, 0)
#define MFMA32(a, b, c) __builtin_amdgcn_mfma_f32_32x32x16_bf16((a), (b), (c), 0, 0, 0)

__device__ __forceinline__ void gload_lds16(const void* g, void* l) {
  __builtin_amdgcn_global_load_lds((__attribute__((address_space(1))) void*)(g),
                                   (__attribute__((address_space(3))) void*)(l),
                                   16, 0, 0);
}

// ---------------- fp32 -> bf16 conversion (qkv_w and out_w in one launch) ----------------
__global__ __launch_bounds__(256) void f2bf_kernel(const float* __restrict__ in0,
                                                   bf16* __restrict__ out0,
                                                   const float* __restrict__ in1,
                                                   bf16* __restrict__ out1, int n0) {
  int i = blockIdx.x * 256 + threadIdx.x;
  const float* in = (i < n0) ? in0 : in1;
  bf16* out = (i < n0) ? out0 : out1;
  int j = (i < n0) ? i : i - n0;
  float4 v = ((const float4*)in)[j];
  bf16x4 o;
  o[0] = (bf16)v.x; o[1] = (bf16)v.y; o[2] = (bf16)v.z; o[3] = (bf16)v.w;
  *(bf16x4*)(out + (size_t)j * 4) = o;
}

// ---------------- ns = cond @ norm_w.T + 1 ----------------
__global__ __launch_bounds__(256) void ns_kernel(const float* __restrict__ cond,
                                                 const float* __restrict__ norm_w,
                                                 float* __restrict__ nsp1) {
  int tid = blockIdx.x * 256 + threadIdx.x;  // 8192 = 8 * 1024
  int b = tid >> 10, c = tid & 1023;
  const float4* wv = (const float4*)(norm_w + (size_t)c * 768);
  const float4* cv = (const float4*)(cond + (size_t)b * 768);
  float acc = 0.f;
#pragma unroll 8
  for (int i = 0; i < 192; ++i) {
    float4 w4 = wv[i], c4 = cv[i];
    acc += w4.x * c4.x + w4.y * c4.y + w4.z * c4.z + w4.w * c4.w;
  }
  nsp1[tid] = acc + 1.0f;
}

// ---------------- RMSNorm * (ns+1) -> bf16 ----------------
__global__ __launch_bounds__(256) void rmsnorm_kernel(const float* __restrict__ x,
                                                      const float* __restrict__ nsp1,
                                                      bf16* __restrict__ xn) {
  int lane = threadIdx.x & 63, w = threadIdx.x >> 6;
  int m = blockIdx.x * 4 + w;  // token id, 8192 total
  int b = m >> 10;
  const float* xp = x + (size_t)m * 1024 + lane * 16;
  float v[16];
  float ss = 0.f;
#pragma unroll
  for (int i = 0; i < 4; ++i) {
    float4 t4 = ((const float4*)xp)[i];
    v[4 * i + 0] = t4.x; v[4 * i + 1] = t4.y; v[4 * i + 2] = t4.z; v[4 * i + 3] = t4.w;
    ss += t4.x * t4.x + t4.y * t4.y + t4.z * t4.z + t4.w * t4.w;
  }
#pragma unroll
  for (int off = 32; off >= 1; off >>= 1) ss += __shfl_xor(ss, off);
  float r = rsqrtf(ss * (1.0f / 1024.0f) + 1e-6f);
  const float* np = nsp1 + (size_t)b * 1024 + lane * 16;
  bf16x8 o0, o1;
#pragma unroll
  for (int j = 0; j < 8; ++j) o0[j] = (bf16)(v[j] * np[j] * r);
#pragma unroll
  for (int j = 0; j < 8; ++j) o1[j] = (bf16)(v[8 + j] * np[8 + j] * r);
  bf16* op = xn + (size_t)m * 1024 + lane * 16;
  *(bf16x8*)op = o0;
  *(bf16x8*)(op + 8) = o1;
}

// ======== GEMM for qkv: 256x128 tile, BK=64, ring-3, phase interleave (best: 76.3us) ========
__global__ __launch_bounds__(512, 2) void gemm8p(const bf16* __restrict__ A,
                                                 const bf16* __restrict__ B, int nbn,
                                                 bf16* __restrict__ qout, bf16* __restrict__ kout,
                                                 bf16* __restrict__ vtout,
                                                 const float* __restrict__ pos,
                                                 const float* __restrict__ scale) {
  constexpr int K = 1024;
  __shared__ __align__(16) bf16 sm[73728];  // 3 slots x (A 16384 + B 8192 elems) = 144 KB
  const int t = threadIdx.x;
  const int cpx = gridDim.x >> 3;  // grid % 8 == 0
  const int bid = blockIdx.x;
  const int virt = (bid & 7) * cpx + (bid >> 3);
  const int bn = virt % nbn, bm = virt / nbn;
  const int m0 = bm * 256, n0 = bn * 128;
  const int lane = t & 63, wid = t >> 6;
  const int wr = wid >> 1, wc = wid & 1;  // 4x2 wave grid, wave tile 64x64
  const int r16 = lane & 15, hi = lane >> 4;
  const int sw = r16 & 7;

  const int row0 = t >> 3;
  const int gc = (t & 7) ^ (row0 & 7);
  const bf16* gAb = A + (size_t)(m0 + row0) * K + gc * 8;
  const bf16* gBb = B + (size_t)(n0 + row0) * K + gc * 8;
  const size_t rstep = (size_t)64 * K;
  const int ldst = t * 8;

  int aoff2[4][2], boff2[4][2];
#pragma unroll
  for (int fr = 0; fr < 4; ++fr)
#pragma unroll
    for (int ks = 0; ks < 2; ++ks) {
      aoff2[fr][ks] = (wr * 64 + fr * 16 + r16) * 64 + (((ks * 4 + hi) ^ sw) << 3);
      boff2[fr][ks] = 16384 + (wc * 64 + fr * 16 + r16) * 64 + (((ks * 4 + hi) ^ sw) << 3);
    }

  f32x4 acc[4][4] = {};

#define STG2(tile_, slot_, pr_)                                                       \
  {                                                                                   \
    if ((pr_) < 2) {                                                                  \
      gload_lds16(gAb + rstep * (2 * (pr_)) + (size_t)(tile_) * 64,                   \
                  &sm[(slot_) * 24576 + (2 * (pr_)) * 4096 + ldst]);                  \
      gload_lds16(gAb + rstep * (2 * (pr_) + 1) + (size_t)(tile_) * 64,               \
                  &sm[(slot_) * 24576 + (2 * (pr_) + 1) * 4096 + ldst]);              \
    } else {                                                                          \
      gload_lds16(gBb + (size_t)(tile_) * 64, &sm[(slot_) * 24576 + 16384 + ldst]);   \
      gload_lds16(gBb + rstep + (size_t)(tile_) * 64,                                 \
                  &sm[(slot_) * 24576 + 20480 + ldst]);                               \
    }                                                                                 \
  }

  STG2(0, 0, 0); STG2(0, 0, 1); STG2(0, 0, 2);
  STG2(1, 1, 0); STG2(1, 1, 1); STG2(1, 1, 2);

  int sl = 0, sl2 = 2;
  for (int s = 0; s < 16; ++s) {
    if (s < 15) {
      asm volatile("s_waitcnt vmcnt(6)" ::: "memory");
    } else {
      asm volatile("s_waitcnt vmcnt(0)" ::: "memory");
    }
    __builtin_amdgcn_s_barrier();
    __builtin_amdgcn_sched_barrier(0);
    const bf16* base = &sm[sl * 24576];
    const bool st = (s + 2 < 16);
    bf16x8 ball[4][2], a2[2][2];
#pragma unroll
    for (int fc = 0; fc < 4; ++fc)
#pragma unroll
      for (int ks = 0; ks < 2; ++ks) ball[fc][ks] = *(const bf16x8*)&base[boff2[fc][ks]];
#pragma unroll
    for (int i = 0; i < 2; ++i)
#pragma unroll
      for (int ks = 0; ks < 2; ++ks) a2[i][ks] = *(const bf16x8*)&base[aoff2[i][ks]];
    if (st) { STG2(s + 2, sl2, 0); STG2(s + 2, sl2, 1); }
    asm volatile("s_waitcnt lgkmcnt(0)" ::: "memory");
    __builtin_amdgcn_sched_barrier(0);
    __builtin_amdgcn_s_setprio(1);
#pragma unroll
    for (int ks = 0; ks < 2; ++ks)
#pragma unroll
      for (int fc = 0; fc < 4; ++fc)
#pragma unroll
        for (int i = 0; i < 2; ++i)
          acc[i][fc] = MFMA16(a2[i][ks], ball[fc][ks], acc[i][fc]);
    __builtin_amdgcn_s_setprio(0);
    __builtin_amdgcn_sched_barrier(0);
    __builtin_amdgcn_s_barrier();
    bf16x8 a3[2][2];
#pragma unroll
    for (int i = 0; i < 2; ++i)
#pragma unroll
      for (int ks = 0; ks < 2; ++ks) a3[i][ks] = *(const bf16x8*)&base[aoff2[2 + i][ks]];
    if (st) STG2(s + 2, sl2, 2);
    asm volatile("s_waitcnt lgkmcnt(0)" ::: "memory");
    __builtin_amdgcn_sched_barrier(0);
    __builtin_amdgcn_s_setprio(1);
#pragma unroll
    for (int ks = 0; ks < 2; ++ks)
#pragma unroll
      for (int fc = 0; fc < 4; ++fc)
#pragma unroll
        for (int i = 0; i < 2; ++i)
          acc[2 + i][fc] = MFMA16(a3[i][ks], ball[fc][ks], acc[2 + i][fc]);
    __builtin_amdgcn_s_setprio(0);
    __builtin_amdgcn_sched_barrier(0);
    __builtin_amdgcn_s_barrier();
    sl = (sl == 2) ? 0 : sl + 1;
    sl2 = (sl2 == 2) ? 0 : sl2 + 1;
  }
#undef STG2

  const int p = n0 >> 10;  // uniform per block: 0=q, 1=k, 2=v
  if (p == 2) {
    const int hiq = ((hi & 1) << 1) | (hi >> 1);  // pi quad-swap for attn's b128 V reads
#pragma unroll
    for (int fr = 0; fr < 4; ++fr) {
      int mrow = m0 + wr * 64 + fr * 16 + hiq * 4;
      int b = mrow >> 10, s0 = mrow & 1023;
#pragma unroll
      for (int fc = 0; fc < 4; ++fc) {
        int n = n0 + wc * 64 + fc * 16 + r16;
        int d = n & 63, hh = (n >> 6) & 15;
        bf16x4 pk;
        pk[0] = (bf16)acc[fr][fc][0]; pk[1] = (bf16)acc[fr][fc][1];
        pk[2] = (bf16)acc[fr][fc][2]; pk[3] = (bf16)acc[fr][fc][3];
        *(bf16x4*)&vtout[(((size_t)(b * 16 + hh) * 64 + d) << 10) + s0] = pk;
      }
    }
  } else {
    const int hh = ((n0 + wc * 64) >> 6) & 15;
    const float LOG2E = 1.4426950408889634f;
    const float sqv = sqrtf(scale[hh]) * (p == 0 ? LOG2E : 1.0f);
    const float f = __expf(1.14472988584940017f +
                           0.0179897502011134460f * (float)((r16 & 7) * 16 + hh));
    const bool is_h = (r16 < 8);
    bf16* dst = (p == 0) ? qout : kout;
#pragma unroll
    for (int fr = 0; fr < 4; ++fr) {
      int mrow = m0 + wr * 64 + fr * 16 + hi * 4;
      int b = mrow >> 10, s0 = mrow & 1023;
      float rr[4];
#pragma unroll
      for (int r = 0; r < 4; ++r) {
        float ss = acc[fr][0][r] * acc[fr][0][r] + acc[fr][1][r] * acc[fr][1][r] +
                   acc[fr][2][r] * acc[fr][2][r] + acc[fr][3][r] * acc[fr][3][r];
        ss += __shfl_xor(ss, 1);
        ss += __shfl_xor(ss, 2);
        ss += __shfl_xor(ss, 4);
        ss += __shfl_xor(ss, 8);
        rr[r] = sqv * rsqrtf(ss + 1e-6f);
      }
#pragma unroll
      for (int r = 0; r < 4; ++r) {
        float2 pp = *(const float2*)&pos[(((size_t)b << 10) + s0 + r) * 2];
        float th = (is_h ? pp.x : pp.y) * f;
        float sv, cv;
        __sincosf(th, &sv, &cv);
        float x1 = acc[fr][0][r] * rr[r];
        float x2 = acc[fr][1][r] * rr[r];
        size_t rowb = (((size_t)(b * 16 + hh) << 10) + s0 + r) * 64;
        dst[rowb + r16]      = (bf16)(x1 * cv - x2 * sv);
        dst[rowb + 16 + r16] = (bf16)(x2 * cv + x1 * sv);
        dst[rowb + 32 + r16] = (bf16)(acc[fr][2][r] * rr[r]);
        dst[rowb + 48 + r16] = (bf16)(acc[fr][3][r] * rr[r]);
      }
    }
  }
}

// ---------------- 256x128-tile GEMM, ring-3 BK=32 — out-proj only ----------------
__global__ __launch_bounds__(512, 2) void gemm256b(const bf16* __restrict__ A,
                                                   const bf16* __restrict__ B, int nbn,
                                                   float* __restrict__ fout,
                                                   const float* __restrict__ skip) {
  constexpr int K = 1024;
  __shared__ __align__(16) bf16 sm[36864];  // 3 slots x (A 8192 + B 4096) = 72 KB
  const int t = threadIdx.x;
  const int cpx = gridDim.x >> 3;
  const int bid = blockIdx.x;
  const int virt = (bid & 7) * cpx + (bid >> 3);
  const int bn = virt % nbn, bm = virt / nbn;
  const int m0 = bm * 256, n0 = bn * 128;
  const int lane = t & 63, wid = t >> 6;
  const int wr = wid >> 1, wc = wid & 1;
  const int r16 = lane & 15, hi = lane >> 4;

  const int tq = t >> 3, c8 = t & 7, cp = c8 ^ (tq & 7);
  const size_t gA = (size_t)(m0 + tq * 2 + (cp >> 2)) * K + (cp & 3) * 8;
  const size_t gB = (size_t)(n0 + tq * 2 + (cp >> 2)) * K + (cp & 3) * 8;
  const size_t gj = (size_t)128 * K;
  const int ldst = t * 8;

  const int chunk = ((r16 & 1) * 4 + hi) ^ (r16 >> 1);
  int aoff[4], boff[4];
#pragma unroll
  for (int fr = 0; fr < 4; ++fr) aoff[fr] = (wr * 32 + fr * 8 + (r16 >> 1)) * 64 + chunk * 8;
#pragma unroll
  for (int fc = 0; fc < 4; ++fc)
    boff[fc] = (wc * 32 + fc * 8 + (r16 >> 1)) * 64 + chunk * 8 + 8192;

  f32x4 acc[4][4] = {};
  constexpr int NS = K >> 5;  // 32

#define STG(tile, slot)                                              \
  {                                                                  \
    const bf16* as_ = A + gA + (size_t)(tile) * 32;                  \
    const bf16* bs_ = B + gB + (size_t)(tile) * 32;                  \
    gload_lds16(as_, &sm[(slot) * 12288 + ldst]);                    \
    gload_lds16(as_ + gj, &sm[(slot) * 12288 + 4096 + ldst]);        \
    gload_lds16(bs_, &sm[(slot) * 12288 + 8192 + ldst]);             \
  }

  STG(0, 0);
  STG(1, 1);

  int sl = 0, sl2 = 2;
  for (int s = 0; s < NS; ++s) {
    if (s < NS - 1) {
      asm volatile("s_waitcnt vmcnt(3)" ::: "memory");
    } else {
      asm volatile("s_waitcnt vmcnt(0)" ::: "memory");
    }
    __builtin_amdgcn_s_barrier();
    __builtin_amdgcn_sched_barrier(0);
    if (s + 2 < NS) STG(s + 2, sl2);
    bf16x8 af[4], bfr[4];
    const bf16* base = &sm[sl * 12288];
#pragma unroll
    for (int fr = 0; fr < 4; ++fr) af[fr] = *(const bf16x8*)&base[aoff[fr]];
#pragma unroll
    for (int fc = 0; fc < 4; ++fc) bfr[fc] = *(const bf16x8*)&base[boff[fc]];
    __builtin_amdgcn_s_setprio(1);
#pragma unroll
    for (int fc = 0; fc < 4; ++fc)
#pragma unroll
      for (int fr = 0; fr < 4; ++fr) acc[fr][fc] = MFMA16(af[fr], bfr[fc], acc[fr][fc]);
    __builtin_amdgcn_s_setprio(0);
    sl = (sl == 2) ? 0 : sl + 1;
    sl2 = (sl2 == 2) ? 0 : sl2 + 1;
  }
#undef STG

#pragma unroll
  for (int fr = 0; fr < 4; ++fr) {
    int mrow = m0 + wr * 64 + fr * 16 + hi * 4;
#pragma unroll
    for (int fc = 0; fc < 4; ++fc) {
      int n = n0 + wc * 64 + fc * 16 + r16;
#pragma unroll
      for (int r = 0; r < 4; ++r) {
        size_t off = (size_t)(mrow + r) * 1024 + n;
        fout[off] = acc[fr][fc][r] + skip[off];
      }
    }
  }
}

// ---------------- flash attention v9: 8 waves (QBLK=256), 32x32 MFMA, depth-2 pipeline ----------------
// Same per-wave algorithm as v8b; two 64x64 K/V tiles now shared by 8 waves (2x compute per
// staged byte), staging = 1 K-load + 1 V-load per thread (512 threads cover the tile).
__global__ __launch_bounds__(512, 2) void attn_kernel(const bf16* __restrict__ q,
                                                      const bf16* __restrict__ k,
                                                      const bf16* __restrict__ vt,
                                                      bf16* __restrict__ o) {
  int bid = blockIdx.x;  // 512 blocks
  int virt = (bid & 7) * 64 + (bid >> 3);
  const int bh = virt >> 2;     // (b*16+h)
  const int qt = virt & 3;      // q-tile of 256
  const int b = bh >> 4, h = bh & 15;
  const int t = threadIdx.x, lane = t & 63, w = t >> 6;  // 8 waves
  const int l31 = lane & 31, h2 = lane >> 5;

  __shared__ bf16 lK[2][4096];
  __shared__ bf16 lV[2][4096];

  const bf16* kp = k + (size_t)bh * 65536;
  const bf16* vp = vt + (size_t)bh * 65536;  // (d, s-pi) layout

  // Q B-frags; wave owns q rows qt*256 + w*32 .. +31
  const bf16* qp = q + ((size_t)bh * 1024 + qt * 256 + w * 32) * 64;
  bf16x8 qf[4];
#pragma unroll
  for (int df = 0; df < 4; ++df)
    qf[df] = *(const bf16x8*)&qp[l31 * 64 + df * 16 + h2 * 8];

  bf16x8 ones;
#pragma unroll
  for (int i = 0; i < 8; ++i) ones[i] = (bf16)1.0f;

  // staging: 512 threads cover one 64x64 tile with a single load each
  const int srow0 = t >> 3, sc0 = t & 7;
  const int se = ((sc0 ^ (srow0 & 7)) << 3);

  f32x16 oacc0 = {}, oacc1 = {}, lacc = {};

#define STGA(kt_, buf_)                                                          \
  {                                                                              \
    gload_lds16(kp + (kt_) * 4096 + (size_t)srow0 * 64 + se, &lK[buf_][t * 8]);  \
    gload_lds16(vp + (kt_) * 64 + (size_t)srow0 * 1024 + se, &lV[buf_][t * 8]);  \
  }

  // prologue: stage tiles 0 and 1 (4 loads in flight)
  STGA(0, 0);
  STGA(1, 1);

  for (int kt = 0; kt < 16; ++kt) {
    const int cur = kt & 1;
    if (kt < 15) {
      asm volatile("s_waitcnt vmcnt(2)" ::: "memory");  // drains tile kt; kt+1 stays in flight
    } else {
      asm volatile("s_waitcnt vmcnt(0)" ::: "memory");
    }
    __builtin_amdgcn_s_barrier();
    __builtin_amdgcn_sched_barrier(0);
    // ---- swapped QK^T ----
    f32x16 sa0 = {}, sa1 = {};
    __builtin_amdgcn_s_setprio(1);
#pragma unroll
    for (int df = 0; df < 4; ++df) {
      int sw = l31 & 7;
      int ce = (((2 * df + h2) ^ sw) << 3);
      bf16x8 kf0 = *(const bf16x8*)&lK[cur][l31 * 64 + ce];
      bf16x8 kf1 = *(const bf16x8*)&lK[cur][(32 + l31) * 64 + ce];
      sa0 = MFMA32(kf0, qf[df], sa0);
      sa1 = MFMA32(kf1, qf[df], sa1);
    }
    __builtin_amdgcn_s_setprio(0);
    // ---- shift-free softmax + pi-ordered pack ----
    bf16x8 pa[4];
#pragma unroll
    for (int e = 0; e < 8; ++e) {
      pa[0][e] = (bf16)exp2f(sa0[e]);
      pa[1][e] = (bf16)exp2f(sa0[e + 8]);
      pa[2][e] = (bf16)exp2f(sa1[e]);
      pa[3][e] = (bf16)exp2f(sa1[e + 8]);
    }
    // ---- PV + l (V pi pre-baked; one b128 per frag) ----
    __builtin_amdgcn_s_setprio(1);
#pragma unroll
    for (int pk = 0; pk < 4; ++pk) {
      lacc = MFMA32(pa[pk], ones, lacc);
#pragma unroll
      for (int db = 0; db < 2; ++db) {
        int row = db * 32 + l31, sw = row & 7;
        bf16x8 vf = *(const bf16x8*)&lV[cur][row * 64 + (((2 * pk + h2) ^ sw) << 3)];
        if (db == 0) oacc0 = MFMA32(pa[pk], vf, oacc0);
        else         oacc1 = MFMA32(pa[pk], vf, oacc1);
      }
    }
    __builtin_amdgcn_s_setprio(0);
    __builtin_amdgcn_sched_barrier(0);
    __builtin_amdgcn_s_barrier();
    __builtin_amdgcn_sched_barrier(0);
    if (kt < 14) STGA(kt + 2, cur);  // overwrite buf just consumed (all waves past barrier)
  }
#undef STGA

  f32x16 inv;
#pragma unroll
  for (int r = 0; r < 16; ++r) inv[r] = 1.f / lacc[r];
#pragma unroll
  for (int r = 0; r < 16; ++r) {
    int qrow = qt * 256 + w * 32 + (r & 3) + 8 * (r >> 2) + 4 * h2;
    size_t rowb = ((size_t)b * 1024 + qrow) * 1024 + h * 64;
    o[rowb + l31]      = (bf16)(oacc0[r] * inv[r]);
    o[rowb + 32 + l31] = (bf16)(oacc1[r] * inv[r]);
  }
}

extern "C" void kernel_launch(void* const* d_in, const int* in_sizes, int n_in,
                              void* d_out, int out_size, void* d_ws, size_t ws_size,
                              hipStream_t stream) {
  const float* x      = (const float*)d_in[0];  // (8,32,32,1024)
  const float* pos    = (const float*)d_in[1];  // (8,32,32,2)
  const float* cond   = (const float*)d_in[2];  // (8,768)
  const float* norm_w = (const float*)d_in[3];  // (1024,768)
  const float* qkv_w  = (const float*)d_in[4];  // (3072,1024)
  const float* out_w  = (const float*)d_in[5];  // (1024,1024)
  const float* scale  = (const float*)d_in[6];  // (16,)
  float* out = (float*)d_out;

  char* ws = (char*)d_ws;
  bf16* xn        = (bf16*)(ws + 0);           // 16.8 MB (reused as o_attn)
  bf16* qkv_w_bf  = (bf16*)(ws + 16777216);    // 6.3 MB
  bf16* out_w_bf  = (bf16*)(ws + 23068672);    // 2.1 MB
  float* nsp1     = (float*)(ws + 25165824);   // 32 KB
  bf16* qraw      = (bf16*)(ws + 25198592);    // 16.8 MB
  bf16* kraw      = (bf16*)(ws + 41975808);    // 16.8 MB
  bf16* vt        = (bf16*)(ws + 58753024);    // 16.8 MB
  bf16* o_attn    = xn;

  f2bf_kernel<<<4096, 256, 0, stream>>>(qkv_w, qkv_w_bf, out_w, out_w_bf, 786432);
  ns_kernel<<<32, 256, 0, stream>>>(cond, norm_w, nsp1);
  rmsnorm_kernel<<<2048, 256, 0, stream>>>(x, nsp1, xn);
  gemm8p<<<768, 512, 0, stream>>>(xn, qkv_w_bf, 24, qraw, kraw, vt, pos, scale);
  attn_kernel<<<512, 512, 0, stream>>>(qraw, kraw, vt, o_attn);
  gemm256b<<<256, 512, 0, stream>>>(o_attn, out_w_bf, 8, out, x);
}